// Round 8
// baseline (464.518 us; speedup 1.0000x reference)
//
#include <hip/hip_runtime.h>
#include <hip/hip_bf16.h>

constexpr int N    = 8192;
constexpr int FIN  = 512;
constexpr int FOUT = 64;
constexpr int NSPLIT = 16;           // R18: j-split 16 -> (128,16) grid, 2048 blocks
constexpr int JCHUNK = N / NSPLIT;   // 512 j per block
constexpr int NSLICE = 4;            // internal slices per block
constexpr int JS     = JCHUNK / NSLICE;  // 128 j per LDS staging round
constexpr int LROW   = JS + 8;       // LDS B row pitch in bf16 (136 shorts)
constexpr int MPITCH = 5;            // Ml row pitch in u32 (4 mask words + 1 pad)

typedef __attribute__((ext_vector_type(8))) short short8;
typedef __attribute__((ext_vector_type(4))) float f32x4;

union BF2U { unsigned int u; __hip_bfloat162 h; };

// ---------------------------------------------------------------------------
// Kernel 1: h = input @ W (fp32), fused epilogue:
//   E1=exp(s1), F1=exp(0.2 s1), E2=exp(s2), F2=exp(0.2 s2)  (exp-free k2)
//   + bf16 h^T write (B-operand feed for MFMA).   (R0 verbatim, proven)
// ---------------------------------------------------------------------------
__global__ __launch_bounds__(256) void k1_proj(
    const float* __restrict__ input, const float* __restrict__ W,
    const float* __restrict__ a, __hip_bfloat16* __restrict__ hbT,
    float* __restrict__ E1, float* __restrict__ F1,
    float* __restrict__ E2, float* __restrict__ F2)
{
    __shared__ __hip_bfloat16 tile[8][64];
    const int tid  = threadIdx.x;
    const int col  = tid & 63;
    const int g    = tid >> 6;
    const int rbase = blockIdx.x * 8;

    float acc[2] = {0.f, 0.f};
    const float* in0 = input + (size_t)(rbase + g * 2) * FIN;

    for (int k = 0; k < FIN; k += 8) {
        float w[8];
        #pragma unroll
        for (int q = 0; q < 8; ++q) w[q] = W[(k + q) * FOUT + col];
        const float4 x0a = *(const float4*)(in0 + 0 * FIN + k);
        const float4 x0b = *(const float4*)(in0 + 0 * FIN + k + 4);
        const float4 x1a = *(const float4*)(in0 + 1 * FIN + k);
        const float4 x1b = *(const float4*)(in0 + 1 * FIN + k + 4);
        acc[0] = fmaf(x0a.w, w[3], fmaf(x0a.z, w[2], fmaf(x0a.y, w[1], fmaf(x0a.x, w[0], acc[0]))));
        acc[0] = fmaf(x0b.w, w[7], fmaf(x0b.z, w[6], fmaf(x0b.y, w[5], fmaf(x0b.x, w[4], acc[0]))));
        acc[1] = fmaf(x1a.w, w[3], fmaf(x1a.z, w[2], fmaf(x1a.y, w[1], fmaf(x1a.x, w[0], acc[1]))));
        acc[1] = fmaf(x1b.w, w[7], fmaf(x1b.z, w[6], fmaf(x1b.y, w[5], fmaf(x1b.x, w[4], acc[1]))));
    }

    const float a1c = a[col];
    const float a2c = a[FOUT + col];
    #pragma unroll
    for (int q = 0; q < 2; ++q) {
        float r1 = acc[q] * a1c;
        float r2 = acc[q] * a2c;
        #pragma unroll
        for (int off = 32; off >= 1; off >>= 1) {
            r1 += __shfl_xor(r1, off, 64);
            r2 += __shfl_xor(r2, off, 64);
        }
        if (col == 0) {
            const int i = rbase + g * 2 + q;
            E1[i] = __expf(r1);
            F1[i] = __expf(0.2f * r1);
            E2[i] = __expf(r2);
            F2[i] = __expf(0.2f * r2);
        }
        tile[g * 2 + q][col] = __float2bfloat16(acc[q]);
    }
    __syncthreads();

    if (tid < 128) {
        const int c = tid >> 1, part = tid & 1;
        unsigned short v[4];
        #pragma unroll
        for (int u = 0; u < 4; ++u) {
            __hip_bfloat16 hv = tile[part * 4 + u][c];
            v[u] = *reinterpret_cast<unsigned short*>(&hv);
        }
        *(ushort4*)((unsigned short*)hbT + (size_t)c * N + rbase + part * 4) =
            make_ushort4(v[0], v[1], v[2], v[3]);
    }
}

// ---------------------------------------------------------------------------
// Kernel 2 (R18): attention + PV via MFMA. SINGLE LEVER vs R0 champion:
// occupancy 4 -> 8 blocks/CU. Same inner loop, same staging idioms, same
// rotation & epilogue; tile j-extent halved (NSPLIT 16, JS 128) so LDS drops
// 38.4 -> 19.7 KB (Bl 17.4 + Ml 1.25 + EF 1). launch_bounds(256,8) targets
// <=64 VGPR (R0's loop measured 64). Rationale: R15/R16 counters show all
// pipes <35% (latency/overlap-bound); R16 proved fewer blocks/CU is worse;
// more staggered blocks/CU lets one block's adj/B staging hide under
// another's MFMA/VALU compute.
// ---------------------------------------------------------------------------
__global__ __launch_bounds__(256, 8) void k2_attn(
    const int* __restrict__ adj,
    const float* __restrict__ E1, const float* __restrict__ F1,
    const float* __restrict__ E2, const float* __restrict__ F2,
    const unsigned short* __restrict__ hbT,
    float* __restrict__ pAcc, float* __restrict__ pZ)
{
    __shared__ unsigned short Bl[64 * LROW];      // 17.4 KB, padded rows
    __shared__ unsigned int   Ml[64 * MPITCH];    // 1.25 KB: 4 u32/row + 1 pad
    __shared__ float          E2l[JS];            // 512 B
    __shared__ float          F2l[JS];            // 512 B

    const int r   = blockIdx.x;
    const int s   = blockIdx.y;
    const int tid = threadIdx.x;
    const int w     = tid >> 6;
    const int lane  = tid & 63;
    const int row16 = lane & 15;
    const int quad  = lane >> 4;
    const int half  = lane >> 5;    // adj staging: 2 rows per wave-load
    const int l32   = lane & 31;

    const int iloc = w * 16 + row16;
    const int i    = r * 64 + iloc;
    const float E1i = E1[i];
    const float F1i = F1[i];

    short8 ones;
    #pragma unroll
    for (int q = 0; q < 8; ++q) ones[q] = (short)0x3F80;   // bf16 1.0

    f32x4 acc0 = {0.f, 0.f, 0.f, 0.f};
    f32x4 acc1 = {0.f, 0.f, 0.f, 0.f};
    f32x4 acc2 = {0.f, 0.f, 0.f, 0.f};
    f32x4 acc3 = {0.f, 0.f, 0.f, 0.f};
    f32x4 accz = {0.f, 0.f, 0.f, 0.f};

    for (int slix = 0; slix < NSLICE; ++slix) {
        const int sl   = (slix + r) & (NSLICE - 1);   // rotated slice order (R0)
        const int jbeg = s * JCHUNK + sl * JS;

        // ---- stage adj slice (64 rows x 512B) and bit-pack into Ml ----
        // Half-wave per row: 32 lanes x int4 = 128 ints = one row-slice.
        {
            unsigned char* Mlb = (unsigned char*)Ml;   // row pitch 20 bytes
            #pragma unroll
            for (int it = 0; it < 8; ++it) {
                const int rloc = it * 8 + w * 2 + half;
                const int4 av = *(const int4*)(adj + (size_t)(r * 64 + rloc) * N + jbeg + l32 * 4);
                unsigned int nib =
                    (av.x != 0 ? 1u : 0u) | (av.y != 0 ? 2u : 0u) |
                    (av.z != 0 ? 4u : 0u) | (av.w != 0 ? 8u : 0u);
                const unsigned int other = __shfl_xor(nib, 1, 64);
                if (!(lane & 1))
                    Mlb[rloc * 20 + (l32 >> 1)] = (unsigned char)(nib | (other << 4));
            }
        }
        // ---- stage B: 64 feature rows x 128 bf16 ----
        #pragma unroll
        for (int rr = 0; rr < 4; ++rr) {
            const int seg = rr * 256 + tid;        // [0, 1024) 16B-segments
            const int f = seg >> 4, o = seg & 15;
            const short8 v = *(const short8*)((const short*)hbT + (size_t)f * N + jbeg + o * 8);
            *(short8*)(&Bl[f * LROW + o * 8]) = v;
        }
        // ---- stage E2/F2 slices (2 x 128 floats, one load/thread) ----
        if (tid < JS) E2l[tid]      = E2[jbeg + tid];
        else          F2l[tid - JS] = F2[jbeg + tid - JS];
        __syncthreads();

        #pragma unroll
        for (int it = 0; it < JS / 32; ++it) {     // 4 iterations
            const int jj = it * 32 + quad * 8;

            const unsigned int mword = Ml[iloc * MPITCH + it];
            const unsigned int mbyte = (mword >> (8 * quad)) & 0xffu;

            const float4 eA = *(const float4*)(&E2l[jj]);
            const float4 eB = *(const float4*)(&E2l[jj + 4]);
            const float4 fA = *(const float4*)(&F2l[jj]);
            const float4 fB = *(const float4*)(&F2l[jj + 4]);

            const short8 b0 = *(const short8*)(&Bl[(row16 +  0) * LROW + jj]);
            const short8 b1 = *(const short8*)(&Bl[(row16 + 16) * LROW + jj]);
            const short8 b2 = *(const short8*)(&Bl[(row16 + 32) * LROW + jj]);
            const short8 b3 = *(const short8*)(&Bl[(row16 + 48) * LROW + jj]);

            float e2v[8], f2v[8];
            e2v[0] = eA.x; e2v[1] = eA.y; e2v[2] = eA.z; e2v[3] = eA.w;
            e2v[4] = eB.x; e2v[5] = eB.y; e2v[6] = eB.z; e2v[7] = eB.w;
            f2v[0] = fA.x; f2v[1] = fA.y; f2v[2] = fA.z; f2v[3] = fA.w;
            f2v[4] = fB.x; f2v[5] = fB.y; f2v[6] = fB.z; f2v[7] = fB.w;

            float pv[8];
            #pragma unroll
            for (int j = 0; j < 8; ++j) {
                // exp(leakyrelu(s1+s2)) == max(E1*E2, F1*F2) exactly
                float p = fmaxf(E1i * e2v[j], F1i * f2v[j]);
                pv[j] = ((mbyte >> j) & 1u) ? p : 0.f;
            }

            short8 afrag;
            #pragma unroll
            for (int jp = 0; jp < 4; ++jp) {       // packed bf16 cvt (RNE)
                BF2U cv;
                cv.h = __float22bfloat162_rn(make_float2(pv[2 * jp], pv[2 * jp + 1]));
                afrag[2 * jp]     = (short)(cv.u & 0xffffu);
                afrag[2 * jp + 1] = (short)(cv.u >> 16);
            }

            acc0 = __builtin_amdgcn_mfma_f32_16x16x32_bf16(afrag, b0, acc0, 0, 0, 0);
            acc1 = __builtin_amdgcn_mfma_f32_16x16x32_bf16(afrag, b1, acc1, 0, 0, 0);
            acc2 = __builtin_amdgcn_mfma_f32_16x16x32_bf16(afrag, b2, acc2, 0, 0, 0);
            acc3 = __builtin_amdgcn_mfma_f32_16x16x32_bf16(afrag, b3, acc3, 0, 0, 0);
            accz = __builtin_amdgcn_mfma_f32_16x16x32_bf16(afrag, ones, accz, 0, 0, 0);
        }
        __syncthreads();   // LDS reuse safety before next slice restage
    }

    // z epilogue: D row m = quad*4+reg (duplicated across the 16 col-lanes)
    if (row16 == 0) {
        #pragma unroll
        for (int reg = 0; reg < 4; ++reg)
            pZ[(size_t)s * N + r * 64 + w * 16 + quad * 4 + reg] = accz[reg];
    }

    // out-tile: C/D layout col=lane&15, row=quad*4+reg
    float* outp = pAcc + ((size_t)s * N + (size_t)r * 64 + w * 16) * FOUT;
    #pragma unroll
    for (int reg = 0; reg < 4; ++reg) {
        const int row = quad * 4 + reg;
        outp[row * FOUT + ( 0 + row16)] = acc0[reg];
        outp[row * FOUT + (16 + row16)] = acc1[reg];
        outp[row * FOUT + (32 + row16)] = acc2[reg];
        outp[row * FOUT + (48 + row16)] = acc3[reg];
    }
}

// ---------------------------------------------------------------------------
// Kernel 3: out[i][f] = sum_s pAcc[s][i][f] / sum_s pZ[s][i]
// ---------------------------------------------------------------------------
__global__ __launch_bounds__(256) void k3_combine(
    const float* __restrict__ pAcc, const float* __restrict__ pZ,
    float* __restrict__ out)
{
    const int idx = blockIdx.x * 256 + threadIdx.x;
    const int i = idx >> 6;
    float num = 0.f, den = 0.f;
    #pragma unroll
    for (int s = 0; s < NSPLIT; ++s) {
        num += pAcc[(size_t)s * N * FOUT + idx];
        den += pZ[(size_t)s * N + i];
    }
    out[idx] = num / den;
}

// ---------------------------------------------------------------------------
extern "C" void kernel_launch(void* const* d_in, const int* in_sizes, int n_in,
                              void* d_out, int out_size, void* d_ws, size_t ws_size,
                              hipStream_t stream)
{
    const float* input = (const float*)d_in[0];
    const int*   adj   = (const int*)d_in[1];
    const float* W     = (const float*)d_in[2];
    const float* a     = (const float*)d_in[3];
    float* out = (float*)d_out;

    char* ws = (char*)d_ws;
    __hip_bfloat16* hbT = (__hip_bfloat16*)ws;               // 1 MB
    float* E1   = (float*)(ws + (size_t)FOUT * N * 2);       // 32 KB
    float* F1   = E1 + N;                                    // 32 KB
    float* E2   = F1 + N;                                    // 32 KB
    float* F2   = E2 + N;                                    // 32 KB
    float* pZ   = F2 + N;                                    // NSPLIT*N*4 = 512 KB
    float* pAcc = pZ + (size_t)NSPLIT * N;                   // 33.6 MB

    k1_proj<<<N / 8, 256, 0, stream>>>(input, W, a, hbT, E1, F1, E2, F2);

    dim3 g2(N / 64, NSPLIT);
    k2_attn<<<g2, 256, 0, stream>>>(adj, E1, F1, E2, F2,
                                    (const unsigned short*)hbT, pAcc, pZ);

    k3_combine<<<(N * FOUT) / 256, 256, 0, stream>>>(pAcc, pZ, out);
}

// Round 9
// 434.910 us; speedup vs baseline: 1.0681x; 1.0681x over previous
//
#include <hip/hip_runtime.h>
#include <hip/hip_bf16.h>

constexpr int N    = 8192;
constexpr int FIN  = 512;
constexpr int FOUT = 64;
constexpr int NSPLIT = 8;            // j-split across blocks -> 1024 blocks, co-resident
constexpr int JCHUNK = N / NSPLIT;   // 1024 j per block
constexpr int NSLICE = 4;            // internal slices per block
constexpr int JS     = JCHUNK / NSLICE;  // 256 j per LDS staging round
constexpr int LROW   = JS + 8;       // LDS B row pitch in bf16 (264 shorts)

typedef __attribute__((ext_vector_type(8))) short short8;
typedef __attribute__((ext_vector_type(4))) float f32x4;

union BF2U { unsigned int u; __hip_bfloat162 h; };

// ---------------------------------------------------------------------------
// CHAMPION RESTORE (R19). This is the R0/R10 source verbatim — measured
// 432.3/434.1 us. Six counter-informed perturbations of k2 (R11 pack kernel,
// R13 reg-mask pipeline, R16 up-front staging, R17 global EF, R18 8 blocks/CU)
// all regressed +18..+51 us; counters show no saturated pipe (VALU 30%,
// HBM 29%, LDS ~30%, Mfma 6%) => mixed-tier contention/latency regime where
// this interleaved stage/compute at 4 blocks/CU is the verified local optimum.
// ---------------------------------------------------------------------------

// Kernel 1: h = input @ W (fp32), fused epilogue:
//   E1=exp(s1), F1=exp(0.2 s1), E2=exp(s2), F2=exp(0.2 s2)  (exp-free k2)
//   + bf16 h^T write (B-operand feed for MFMA).
__global__ __launch_bounds__(256) void k1_proj(
    const float* __restrict__ input, const float* __restrict__ W,
    const float* __restrict__ a, __hip_bfloat16* __restrict__ hbT,
    float* __restrict__ E1, float* __restrict__ F1,
    float* __restrict__ E2, float* __restrict__ F2)
{
    __shared__ __hip_bfloat16 tile[8][64];
    const int tid  = threadIdx.x;
    const int col  = tid & 63;
    const int g    = tid >> 6;
    const int rbase = blockIdx.x * 8;

    float acc[2] = {0.f, 0.f};
    const float* in0 = input + (size_t)(rbase + g * 2) * FIN;

    for (int k = 0; k < FIN; k += 8) {
        float w[8];
        #pragma unroll
        for (int q = 0; q < 8; ++q) w[q] = W[(k + q) * FOUT + col];
        const float4 x0a = *(const float4*)(in0 + 0 * FIN + k);
        const float4 x0b = *(const float4*)(in0 + 0 * FIN + k + 4);
        const float4 x1a = *(const float4*)(in0 + 1 * FIN + k);
        const float4 x1b = *(const float4*)(in0 + 1 * FIN + k + 4);
        acc[0] = fmaf(x0a.w, w[3], fmaf(x0a.z, w[2], fmaf(x0a.y, w[1], fmaf(x0a.x, w[0], acc[0]))));
        acc[0] = fmaf(x0b.w, w[7], fmaf(x0b.z, w[6], fmaf(x0b.y, w[5], fmaf(x0b.x, w[4], acc[0]))));
        acc[1] = fmaf(x1a.w, w[3], fmaf(x1a.z, w[2], fmaf(x1a.y, w[1], fmaf(x1a.x, w[0], acc[1]))));
        acc[1] = fmaf(x1b.w, w[7], fmaf(x1b.z, w[6], fmaf(x1b.y, w[5], fmaf(x1b.x, w[4], acc[1]))));
    }

    const float a1c = a[col];
    const float a2c = a[FOUT + col];
    #pragma unroll
    for (int q = 0; q < 2; ++q) {
        float r1 = acc[q] * a1c;
        float r2 = acc[q] * a2c;
        #pragma unroll
        for (int off = 32; off >= 1; off >>= 1) {
            r1 += __shfl_xor(r1, off, 64);
            r2 += __shfl_xor(r2, off, 64);
        }
        if (col == 0) {
            const int i = rbase + g * 2 + q;
            E1[i] = __expf(r1);
            F1[i] = __expf(0.2f * r1);
            E2[i] = __expf(r2);
            F2[i] = __expf(0.2f * r2);
        }
        tile[g * 2 + q][col] = __float2bfloat16(acc[q]);
    }
    __syncthreads();

    if (tid < 128) {
        const int c = tid >> 1, part = tid & 1;
        unsigned short v[4];
        #pragma unroll
        for (int u = 0; u < 4; ++u) {
            __hip_bfloat16 hv = tile[part * 4 + u][c];
            v[u] = *reinterpret_cast<unsigned short*>(&hv);
        }
        *(ushort4*)((unsigned short*)hbT + (size_t)c * N + rbase + part * 4) =
            make_ushort4(v[0], v[1], v[2], v[3]);
    }
}

// ---------------------------------------------------------------------------
// Kernel 2: attention + PV via MFMA (champion structure, slice rotation).
// ---------------------------------------------------------------------------
__global__ __launch_bounds__(256, 4) void k2_attn(
    const int* __restrict__ adj,
    const float* __restrict__ E1, const float* __restrict__ F1,
    const float* __restrict__ E2, const float* __restrict__ F2,
    const unsigned short* __restrict__ hbT,
    float* __restrict__ pAcc, float* __restrict__ pZ)
{
    __shared__ unsigned short Bl[64 * LROW];   // 33.8 KB, padded rows
    __shared__ unsigned int   Ml[64 * 9];      // bitmask: 8 u32/row + 1 pad word
    __shared__ float          E2l[JS];         // 1 KB
    __shared__ float          F2l[JS];         // 1 KB

    const int r   = blockIdx.x;
    const int s   = blockIdx.y;
    const int tid = threadIdx.x;
    const int w     = tid >> 6;
    const int lane  = tid & 63;
    const int row16 = lane & 15;
    const int quad  = lane >> 4;

    const int iloc = w * 16 + row16;
    const int i    = r * 64 + iloc;
    const float E1i = E1[i];
    const float F1i = F1[i];

    short8 ones;
    #pragma unroll
    for (int q = 0; q < 8; ++q) ones[q] = (short)0x3F80;   // bf16 1.0

    f32x4 acc0 = {0.f, 0.f, 0.f, 0.f};
    f32x4 acc1 = {0.f, 0.f, 0.f, 0.f};
    f32x4 acc2 = {0.f, 0.f, 0.f, 0.f};
    f32x4 acc3 = {0.f, 0.f, 0.f, 0.f};
    f32x4 accz = {0.f, 0.f, 0.f, 0.f};

    for (int slix = 0; slix < NSLICE; ++slix) {
        const int sl   = (slix + r) & (NSLICE - 1);   // rotated slice order
        const int jbeg = s * JCHUNK + sl * JS;

        // ---- stage adj slice (64 rows x 1KB) and bit-pack into Ml ----
        {
            unsigned char* Mlb = (unsigned char*)Ml;   // row pitch 36 bytes
            #pragma unroll
            for (int it = 0; it < 16; ++it) {
                const int rloc = it * 4 + w;
                const int4 av = *(const int4*)(adj + (size_t)(r * 64 + rloc) * N + jbeg + lane * 4);
                unsigned int nib =
                    (av.x != 0 ? 1u : 0u) | (av.y != 0 ? 2u : 0u) |
                    (av.z != 0 ? 4u : 0u) | (av.w != 0 ? 8u : 0u);
                const unsigned int other = __shfl_xor(nib, 1, 64);
                if (!(lane & 1))
                    Mlb[rloc * 36 + (lane >> 1)] = (unsigned char)(nib | (other << 4));
            }
        }
        // ---- stage B: 64 feature rows x 256 bf16 ----
        #pragma unroll
        for (int rr = 0; rr < 8; ++rr) {
            const int seg = rr * 256 + tid;        // [0, 2048) 16B-segments
            const int f = seg >> 5, o = seg & 31;
            const short8 v = *(const short8*)((const short*)hbT + (size_t)f * N + jbeg + o * 8);
            *(short8*)(&Bl[f * LROW + o * 8]) = v;
        }
        // ---- stage E2/F2 slices (JS == 256 == blockDim) ----
        E2l[tid] = E2[jbeg + tid];
        F2l[tid] = F2[jbeg + tid];
        __syncthreads();

        #pragma unroll
        for (int it = 0; it < JS / 32; ++it) {     // 8 iterations
            const int jj = it * 32 + quad * 8;

            const unsigned int mword = Ml[iloc * 9 + it];
            const unsigned int mbyte = (mword >> (8 * quad)) & 0xffu;

            const float4 eA = *(const float4*)(&E2l[jj]);
            const float4 eB = *(const float4*)(&E2l[jj + 4]);
            const float4 fA = *(const float4*)(&F2l[jj]);
            const float4 fB = *(const float4*)(&F2l[jj + 4]);

            const short8 b0 = *(const short8*)(&Bl[(row16 +  0) * LROW + jj]);
            const short8 b1 = *(const short8*)(&Bl[(row16 + 16) * LROW + jj]);
            const short8 b2 = *(const short8*)(&Bl[(row16 + 32) * LROW + jj]);
            const short8 b3 = *(const short8*)(&Bl[(row16 + 48) * LROW + jj]);

            float e2v[8], f2v[8];
            e2v[0] = eA.x; e2v[1] = eA.y; e2v[2] = eA.z; e2v[3] = eA.w;
            e2v[4] = eB.x; e2v[5] = eB.y; e2v[6] = eB.z; e2v[7] = eB.w;
            f2v[0] = fA.x; f2v[1] = fA.y; f2v[2] = fA.z; f2v[3] = fA.w;
            f2v[4] = fB.x; f2v[5] = fB.y; f2v[6] = fB.z; f2v[7] = fB.w;

            float pv[8];
            #pragma unroll
            for (int j = 0; j < 8; ++j) {
                // exp(leakyrelu(s1+s2)) == max(E1*E2, F1*F2) exactly
                float p = fmaxf(E1i * e2v[j], F1i * f2v[j]);
                pv[j] = ((mbyte >> j) & 1u) ? p : 0.f;
            }

            short8 afrag;
            #pragma unroll
            for (int jp = 0; jp < 4; ++jp) {       // packed bf16 cvt (RNE)
                BF2U cv;
                cv.h = __float22bfloat162_rn(make_float2(pv[2 * jp], pv[2 * jp + 1]));
                afrag[2 * jp]     = (short)(cv.u & 0xffffu);
                afrag[2 * jp + 1] = (short)(cv.u >> 16);
            }

            acc0 = __builtin_amdgcn_mfma_f32_16x16x32_bf16(afrag, b0, acc0, 0, 0, 0);
            acc1 = __builtin_amdgcn_mfma_f32_16x16x32_bf16(afrag, b1, acc1, 0, 0, 0);
            acc2 = __builtin_amdgcn_mfma_f32_16x16x32_bf16(afrag, b2, acc2, 0, 0, 0);
            acc3 = __builtin_amdgcn_mfma_f32_16x16x32_bf16(afrag, b3, acc3, 0, 0, 0);
            accz = __builtin_amdgcn_mfma_f32_16x16x32_bf16(afrag, ones, accz, 0, 0, 0);
        }
        __syncthreads();   // LDS reuse safety before next slice restage
    }

    // z epilogue: D row m = quad*4+reg (duplicated across the 16 col-lanes)
    if (row16 == 0) {
        #pragma unroll
        for (int reg = 0; reg < 4; ++reg)
            pZ[(size_t)s * N + r * 64 + w * 16 + quad * 4 + reg] = accz[reg];
    }

    // out-tile: C/D layout col=lane&15, row=quad*4+reg
    float* outp = pAcc + ((size_t)s * N + (size_t)r * 64 + w * 16) * FOUT;
    #pragma unroll
    for (int reg = 0; reg < 4; ++reg) {
        const int row = quad * 4 + reg;
        outp[row * FOUT + ( 0 + row16)] = acc0[reg];
        outp[row * FOUT + (16 + row16)] = acc1[reg];
        outp[row * FOUT + (32 + row16)] = acc2[reg];
        outp[row * FOUT + (48 + row16)] = acc3[reg];
    }
}

// ---------------------------------------------------------------------------
// Kernel 3: out[i][f] = sum_s pAcc[s][i][f] / sum_s pZ[s][i]
// ---------------------------------------------------------------------------
__global__ __launch_bounds__(256) void k3_combine(
    const float* __restrict__ pAcc, const float* __restrict__ pZ,
    float* __restrict__ out)
{
    const int idx = blockIdx.x * 256 + threadIdx.x;
    const int i = idx >> 6;
    float num = 0.f, den = 0.f;
    #pragma unroll
    for (int s = 0; s < NSPLIT; ++s) {
        num += pAcc[(size_t)s * N * FOUT + idx];
        den += pZ[(size_t)s * N + i];
    }
    out[idx] = num / den;
}

// ---------------------------------------------------------------------------
extern "C" void kernel_launch(void* const* d_in, const int* in_sizes, int n_in,
                              void* d_out, int out_size, void* d_ws, size_t ws_size,
                              hipStream_t stream)
{
    const float* input = (const float*)d_in[0];
    const int*   adj   = (const int*)d_in[1];
    const float* W     = (const float*)d_in[2];
    const float* a     = (const float*)d_in[3];
    float* out = (float*)d_out;

    char* ws = (char*)d_ws;
    __hip_bfloat16* hbT = (__hip_bfloat16*)ws;               // 1 MB
    float* E1   = (float*)(ws + (size_t)FOUT * N * 2);       // 32 KB
    float* F1   = E1 + N;                                    // 32 KB
    float* E2   = F1 + N;                                    // 32 KB
    float* F2   = E2 + N;                                    // 32 KB
    float* pZ   = F2 + N;                                    // NSPLIT*N*4 = 256 KB
    float* pAcc = pZ + (size_t)NSPLIT * N;                   // 16.8 MB

    k1_proj<<<N / 8, 256, 0, stream>>>(input, W, a, hbT, E1, F1, E2, F2);

    dim3 g2(N / 64, NSPLIT);
    k2_attn<<<g2, 256, 0, stream>>>(adj, E1, F1, E2, F2,
                                    (const unsigned short*)hbT, pAcc, pZ);

    k3_combine<<<(N * FOUT) / 256, 256, 0, stream>>>(pAcc, pZ, out);
}